// Round 4
// baseline (1435.358 us; speedup 1.0000x reference)
//
#include <hip/hip_runtime.h>

typedef unsigned int uint;

#define D_IN 128
#define D_H  128
#define D_OUT 16
#define BSH 4                  // 16 nodes per fine bucket
#define BNODES (1 << BSH)
#define NPC 128                // nodes per coarse bucket
#define CLDS 800               // >= C = ceil(N/NPC) = 782
#define P1 256                 // pass-1 blocks

static __device__ __forceinline__ float bflo(uint u) { return __uint_as_float(u << 16); }
static __device__ __forceinline__ float bfhi(uint u) { return __uint_as_float(u & 0xFFFF0000u); }
static __device__ __forceinline__ uint f2bf(float f) {
    uint b = __float_as_uint(f);
    return (b + 0x7FFFu + ((b >> 16) & 1u)) >> 16;  // RNE
}
static __device__ __forceinline__ uint pk(float a, float b) {
    return f2bf(a) | (f2bf(b) << 16);
}

// ---- pass 1: coarse histogram (private LDS, no global atomics) -------------

__global__ __launch_bounds__(256) void k_p1hist(const int* __restrict__ dst, int E, int N, int C,
                                                int chunk, int* __restrict__ hist1) {
    __shared__ int h[CLDS];
    int t = threadIdx.x, b = blockIdx.x;
    for (int i = t; i < C; i += 256) h[i] = 0;
    __syncthreads();
    int e0 = b * chunk, e1 = min(e0 + chunk, E);
    for (int e = e0 + t; e < e1; e += 256) {
        int d = dst[e];
        d = max(0, min(d, N - 1));
        atomicAdd(&h[d >> 7], 1);  // NPC=128
    }
    __syncthreads();
    int* hg = hist1 + (size_t)b * C;
    for (int i = t; i < C; i += 256) hg[i] = h[i];
}

// fused: column sums -> exclusive scan -> convert hist1 to per-(block,bucket) cursors
__global__ __launch_bounds__(1024) void k_p1scan(int* __restrict__ hist1, int C,
                                                 int* __restrict__ cbase) {
    __shared__ int col[CLDS];
    __shared__ int sdata[1024];
    int t = threadIdx.x;
    for (int i = t; i < C; i += 1024) {
        int sum = 0;
        for (int b = 0; b < P1; b++) sum += hist1[(size_t)b * C + i];
        col[i] = sum;
    }
    __syncthreads();
    int v = (t < C) ? col[t] : 0;
    sdata[t] = v;
    __syncthreads();
    for (int off = 1; off < 1024; off <<= 1) {
        int x = (t >= off) ? sdata[t - off] : 0;
        __syncthreads();
        sdata[t] += x;
        __syncthreads();
    }
    int pos = sdata[t] - v;  // exclusive
    if (t < C) cbase[t] = pos;
    if (t == 1023) cbase[C] = sdata[1023];
    // poff: hist1[b][i] -> global write cursor start
    if (t < C) {
        int run = pos;
        for (int b = 0; b < P1; b++) {
            size_t idx = (size_t)b * C + t;
            int c = hist1[idx];
            hist1[idx] = run;
            run += c;
        }
    }
}

// scatter packed (dlocal_coarse<<17 | src) into coarse regions, LDS cursors only
__global__ __launch_bounds__(256) void k_p1fill(const int* __restrict__ src,
                                                const int* __restrict__ dst, int E, int N, int C,
                                                int chunk, const int* __restrict__ hist1,
                                                uint* __restrict__ binned1) {
    __shared__ int cur[CLDS];
    int t = threadIdx.x, b = blockIdx.x;
    const int* hg = hist1 + (size_t)b * C;
    for (int i = t; i < C; i += 256) cur[i] = hg[i];
    __syncthreads();
    int e0 = b * chunk, e1 = min(e0 + chunk, E);
    for (int e = e0 + t; e < e1; e += 256) {
        int d = dst[e];
        d = max(0, min(d, N - 1));
        int s = src[e];
        s = max(0, min(s, N - 1));
        int p = atomicAdd(&cur[d >> 7], 1);
        binned1[p] = ((uint)(d & (NPC - 1)) << 17) | (uint)s;
    }
}

// pass 2: one block per coarse bucket -> node-sorted edges, dinv, fine-bucket bbase
__global__ __launch_bounds__(256) void k_p2(const uint* __restrict__ binned1,
                                            const int* __restrict__ cbase, int N, int nbk,
                                            uint* __restrict__ binned2, int* __restrict__ bbase,
                                            float* __restrict__ dinv) {
    __shared__ int ncnt[NPC], nbase_[NPC];
    int c = blockIdx.x, t = threadIdx.x;
    int start = cbase[c], end = cbase[c + 1];
    if (t < NPC) ncnt[t] = 0;
    __syncthreads();
    for (int j = start + t; j < end; j += 256) atomicAdd(&ncnt[binned1[j] >> 17], 1);
    __syncthreads();
    if (t == 0) {
        int run = start;
        for (int i = 0; i < NPC; i++) {
            nbase_[i] = run;
            run += ncnt[i];
        }
    }
    __syncthreads();
    if (t < NPC) {
        int node = c * NPC + t;
        if (node < N) dinv[node] = rsqrtf((float)ncnt[t] + 1.0f);
        if ((t & (BNODES - 1)) == 0) {
            int fb = (c * NPC + t) >> BSH;
            if (fb < nbk) bbase[fb] = nbase_[t];
        }
    }
    if (t == 0 && c == gridDim.x - 1) bbase[nbk] = end;
    __syncthreads();
    if (t < NPC) ncnt[t] = nbase_[t];  // reuse as cursors
    __syncthreads();
    for (int j = start + t; j < end; j += 256) {
        uint pe = binned1[j];
        int dlc = pe >> 17;
        int p = atomicAdd(&ncnt[dlc], 1);
        binned2[p] = ((uint)(dlc & (BNODES - 1)) << 17) | (pe & 0x1FFFFu);
    }
}

// ---- GEMM1: hs_b = bf16( dinv[i] * (x @ W1) ) ------------------------------

__global__ __launch_bounds__(256) void k_gemm1(const float* __restrict__ x,
                                               const float* __restrict__ W1,
                                               const float* __restrict__ dinv, int N,
                                               uint* __restrict__ hs_b) {
    __shared__ float Wl[8 * 516];
    __shared__ float xl[32 * 132];
    int t = threadIdx.x;
    int fg = t & 7, rs = t >> 3;
    int row0 = blockIdx.x * 128;
    float acc[4][16];
#pragma unroll
    for (int a = 0; a < 4; a++)
#pragma unroll
        for (int b = 0; b < 16; b++) acc[a][b] = 0.f;

    for (int cb = 0; cb < 4; cb++) {
        __syncthreads();
        for (int i = t; i < 4096; i += 256) {
            int kk = i >> 7, f = i & 127;
            Wl[(f >> 4) * 516 + kk * 16 + (f & 15)] = W1[(size_t)(cb * 32 + kk) * 128 + f];
        }
        for (int i = t; i < 4096; i += 256) {
            int r = i >> 5, kk = i & 31;
            int gr = row0 + r;
            xl[kk * 132 + r] = (gr < N) ? x[(size_t)gr * 128 + cb * 32 + kk] : 0.f;
        }
        __syncthreads();
        const float* wb = &Wl[fg * 516];
        const float* xb = &xl[rs * 4];
#pragma unroll 4
        for (int kk = 0; kk < 32; kk++) {
            float4 xv = *(const float4*)&xb[kk * 132];
            float4 w0 = *(const float4*)&wb[kk * 16];
            float4 w1 = *(const float4*)&wb[kk * 16 + 4];
            float4 w2 = *(const float4*)&wb[kk * 16 + 8];
            float4 w3 = *(const float4*)&wb[kk * 16 + 12];
            float xr[4] = {xv.x, xv.y, xv.z, xv.w};
            float wf[16] = {w0.x, w0.y, w0.z, w0.w, w1.x, w1.y, w1.z, w1.w,
                            w2.x, w2.y, w2.z, w2.w, w3.x, w3.y, w3.z, w3.w};
#pragma unroll
            for (int a = 0; a < 4; a++)
#pragma unroll
                for (int b = 0; b < 16; b++) acc[a][b] = fmaf(xr[a], wf[b], acc[a][b]);
        }
    }
#pragma unroll
    for (int a = 0; a < 4; a++) {
        int gr = row0 + rs * 4 + a;
        if (gr < N) {
            float sc = dinv[gr];
            uint o[8];
#pragma unroll
            for (int q = 0; q < 8; q++) o[q] = pk(acc[a][2 * q] * sc, acc[a][2 * q + 1] * sc);
            *(uint4*)&hs_b[(size_t)gr * 64 + fg * 8] = make_uint4(o[0], o[1], o[2], o[3]);
            *(uint4*)&hs_b[(size_t)gr * 64 + fg * 8 + 4] = make_uint4(o[4], o[5], o[6], o[7]);
        }
    }
}

// ---- AGG1: bucket-LDS accumulate, rh_b = bf16(relu(dinv*(sum+self)+b1)) ----
// uint j of a row holds features (2j, 2j+1). LDS even/odd split: bank-conflict-free.

__global__ __launch_bounds__(256) void k_agg1(const uint* __restrict__ hs_b,
                                              const uint* __restrict__ binned2,
                                              const int* __restrict__ bbase,
                                              const float* __restrict__ dinv,
                                              const float* __restrict__ b1, int N,
                                              uint* __restrict__ rh_b) {
    __shared__ float accL[BNODES * 128];  // [dl][0..63]=even feats, [dl][64..127]=odd
    int t = threadIdx.x;
    for (int i = t; i < BNODES * 128; i += 256) accL[i] = 0.f;
    __syncthreads();
    int b = blockIdx.x;
    int start = bbase[b], cnt = bbase[b + 1] - start;
    int w = t >> 6, lane = t & 63;
    const uint* bp = binned2 + start;
    int j = w;
    for (; j + 12 < cnt; j += 16) {
        uint p0 = bp[j], p1 = bp[j + 4], p2 = bp[j + 8], p3 = bp[j + 12];
        uint h0 = hs_b[(size_t)(p0 & 0x1FFFFu) * 64 + lane];
        uint h1 = hs_b[(size_t)(p1 & 0x1FFFFu) * 64 + lane];
        uint h2 = hs_b[(size_t)(p2 & 0x1FFFFu) * 64 + lane];
        uint h3 = hs_b[(size_t)(p3 & 0x1FFFFu) * 64 + lane];
        int d0 = p0 >> 17, d1 = p1 >> 17, d2 = p2 >> 17, d3 = p3 >> 17;
        atomicAdd(&accL[d0 * 128 + lane], bflo(h0));
        atomicAdd(&accL[d0 * 128 + 64 + lane], bfhi(h0));
        atomicAdd(&accL[d1 * 128 + lane], bflo(h1));
        atomicAdd(&accL[d1 * 128 + 64 + lane], bfhi(h1));
        atomicAdd(&accL[d2 * 128 + lane], bflo(h2));
        atomicAdd(&accL[d2 * 128 + 64 + lane], bfhi(h2));
        atomicAdd(&accL[d3 * 128 + lane], bflo(h3));
        atomicAdd(&accL[d3 * 128 + 64 + lane], bfhi(h3));
    }
    for (; j < cnt; j += 4) {
        uint p0 = bp[j];
        uint h0 = hs_b[(size_t)(p0 & 0x1FFFFu) * 64 + lane];
        int d0 = p0 >> 17;
        atomicAdd(&accL[d0 * 128 + lane], bflo(h0));
        atomicAdd(&accL[d0 * 128 + 64 + lane], bfhi(h0));
    }
    __syncthreads();
    for (int i = t; i < BNODES * 64; i += 256) {
        int dl = i >> 6, jj = i & 63;
        int node = b * BNODES + dl;
        if (node >= N) continue;
        uint sv = hs_b[(size_t)node * 64 + jj];
        float di = dinv[node];
        float ev = accL[dl * 128 + jj] + bflo(sv);
        float ov = accL[dl * 128 + 64 + jj] + bfhi(sv);
        float re = fmaxf(fmaf(ev, di, b1[2 * jj]), 0.f);
        float ro = fmaxf(fmaf(ov, di, b1[2 * jj + 1]), 0.f);
        rh_b[(size_t)node * 64 + jj] = pk(re, ro);
    }
}

// ---- GEMM2: h2_b = bf16( dinv[i] * (rh @ W2) ), one row per thread ---------

__global__ __launch_bounds__(256) void k_gemm2(const uint* __restrict__ rh_b,
                                               const float* __restrict__ W2,
                                               const float* __restrict__ dinv, int N,
                                               uint* __restrict__ h2_b) {
    __shared__ float Wl[D_H * D_OUT];  // 8 KB
    int t = threadIdx.x;
    for (int i = t; i < D_H * D_OUT; i += 256) Wl[i] = W2[i];
    __syncthreads();
    int r = blockIdx.x * 256 + t;
    if (r >= N) return;
    const uint* xrow = rh_b + (size_t)r * 64;
    float acc[16];
#pragma unroll
    for (int f = 0; f < 16; f++) acc[f] = 0.f;
    for (int c = 0; c < 16; c++) {
        uint4 xv = *(const uint4*)(xrow + c * 4);
        uint xs[4] = {xv.x, xv.y, xv.z, xv.w};
#pragma unroll
        for (int u = 0; u < 4; u++) {
            int k = c * 8 + u * 2;
            float x0 = bflo(xs[u]), x1 = bfhi(xs[u]);
            const float* w0 = &Wl[k * 16];
            const float* w1 = &Wl[(k + 1) * 16];
#pragma unroll
            for (int f = 0; f < 16; f++) acc[f] = fmaf(x0, w0[f], acc[f]);
#pragma unroll
            for (int f = 0; f < 16; f++) acc[f] = fmaf(x1, w1[f], acc[f]);
        }
    }
    float sc = dinv[r];
    uint o[8];
#pragma unroll
    for (int q = 0; q < 8; q++) o[q] = pk(acc[2 * q] * sc, acc[2 * q + 1] * sc);
    *(uint4*)&h2_b[(size_t)r * 8] = make_uint4(o[0], o[1], o[2], o[3]);
    *(uint4*)&h2_b[(size_t)r * 8 + 4] = make_uint4(o[4], o[5], o[6], o[7]);
}

// ---- AGG2: out(f32) = dinv*(sum+self) + b2, bucket-LDS ---------------------

__global__ __launch_bounds__(256) void k_agg2(const uint* __restrict__ h2_b,
                                              const uint* __restrict__ binned2,
                                              const int* __restrict__ bbase,
                                              const float* __restrict__ dinv,
                                              const float* __restrict__ b2, int N,
                                              float* __restrict__ out) {
    __shared__ float acc2[BNODES * 16];  // 1 KB
    int t = threadIdx.x;
    for (int i = t; i < BNODES * 16; i += 256) acc2[i] = 0.f;
    __syncthreads();
    int b = blockIdx.x;
    int start = bbase[b], cnt = bbase[b + 1] - start;
    int w = t >> 6, lane = t & 63;
    int es = lane >> 3, jp = lane & 7;
    const uint* bp = binned2 + start;
    for (int jb = w * 8; jb < cnt; jb += 32) {
        int j = jb + es;
        if (j < cnt) {
            uint pe = bp[j];
            int dl = pe >> 17;
            uint hv = h2_b[(size_t)(pe & 0x1FFFFu) * 8 + jp];
            atomicAdd(&acc2[dl * 16 + 2 * jp], bflo(hv));
            atomicAdd(&acc2[dl * 16 + 2 * jp + 1], bfhi(hv));
        }
    }
    __syncthreads();
    int dl = t >> 4, f = t & 15;
    int node = b * BNODES + dl;
    if (node < N) {
        uint sv = h2_b[(size_t)node * 8 + (f >> 1)];
        float self = (f & 1) ? bfhi(sv) : bflo(sv);
        out[(size_t)node * 16 + f] = fmaf(acc2[dl * 16 + f] + self, dinv[node], b2[f]);
    }
}

// ---- launch ----------------------------------------------------------------

extern "C" void kernel_launch(void* const* d_in, const int* in_sizes, int n_in,
                              void* d_out, int out_size, void* d_ws, size_t ws_size,
                              hipStream_t stream) {
    const float* x  = (const float*)d_in[0];
    const int*   ei = (const int*)d_in[1];
    const float* W1 = (const float*)d_in[2];
    const float* b1 = (const float*)d_in[3];
    const float* W2 = (const float*)d_in[4];
    const float* b2 = (const float*)d_in[5];
    int N = in_sizes[0] / D_IN;
    int E = in_sizes[1] / 2;
    const int* src = ei;
    const int* dst = ei + E;
    int nbk = (N + BNODES - 1) / BNODES;   // 6250
    int C = (N + NPC - 1) / NPC;           // 782
    int chunk = (E + P1 - 1) / P1;         // 6250

    char* ws = (char*)d_ws;
    size_t off = 0;
    auto alloc = [&](size_t bytes) -> char* {
        char* p = ws + off;
        off = (off + bytes + 255) & ~(size_t)255;
        return p;
    };
    int*   hist1   = (int*)alloc((size_t)P1 * C * 4);       // 800 KB
    int*   cbase   = (int*)alloc((size_t)(C + 1) * 4);
    int*   bbase   = (int*)alloc((size_t)(nbk + 1) * 4);
    uint*  binned1 = (uint*)alloc((size_t)E * 4);
    uint*  binned2 = (uint*)alloc((size_t)E * 4);
    float* dinv    = (float*)alloc((size_t)N * 4);
    uint*  hs_b    = (uint*)alloc((size_t)N * 64 * 4);      // 25.6 MB bf16-packed
    uint*  rh_b    = (uint*)alloc((size_t)N * 64 * 4);
    uint*  h2_b    = (uint*)alloc((size_t)N * 8 * 4);       // 3.2 MB

    k_p1hist<<<P1, 256, 0, stream>>>(dst, E, N, C, chunk, hist1);
    k_p1scan<<<1, 1024, 0, stream>>>(hist1, C, cbase);
    k_p1fill<<<P1, 256, 0, stream>>>(src, dst, E, N, C, chunk, hist1, binned1);
    k_p2<<<C, 256, 0, stream>>>(binned1, cbase, N, nbk, binned2, bbase, dinv);
    k_gemm1<<<(N + 127) / 128, 256, 0, stream>>>(x, W1, dinv, N, hs_b);
    k_agg1<<<nbk, 256, 0, stream>>>(hs_b, binned2, bbase, dinv, b1, N, rh_b);
    k_gemm2<<<(N + 255) / 256, 256, 0, stream>>>(rh_b, W2, dinv, N, h2_b);
    k_agg2<<<nbk, 256, 0, stream>>>(h2_b, binned2, bbase, dinv, b2, N, (float*)d_out);
}

// Round 5
// 367.224 us; speedup vs baseline: 3.9087x; 3.9087x over previous
//
#include <hip/hip_runtime.h>

typedef unsigned int uint;

#define D_IN 128
#define D_H  128
#define D_OUT 16
#define NPC 128                // nodes per coarse bucket
#define CLDS 800               // >= C = ceil(N/NPC) = 782
#define P1 256                 // pass-1 blocks

static __device__ __forceinline__ float bflo(uint u) { return __uint_as_float(u << 16); }
static __device__ __forceinline__ float bfhi(uint u) { return __uint_as_float(u & 0xFFFF0000u); }
static __device__ __forceinline__ uint f2bf(float f) {
    uint b = __float_as_uint(f);
    return (b + 0x7FFFu + ((b >> 16) & 1u)) >> 16;  // RNE
}
static __device__ __forceinline__ uint pk(float a, float b) {
    return f2bf(a) | (f2bf(b) << 16);
}

// ---- pass 1: coarse histogram (private LDS, no global atomics) -------------

__global__ __launch_bounds__(256) void k_p1hist(const int* __restrict__ dst, int E, int N, int C,
                                                int chunk, int* __restrict__ hist1) {
    __shared__ int h[CLDS];
    int t = threadIdx.x, b = blockIdx.x;
    for (int i = t; i < C; i += 256) h[i] = 0;
    __syncthreads();
    int e0 = b * chunk, e1 = min(e0 + chunk, E);
    for (int e = e0 + t; e < e1; e += 256) {
        int d = dst[e];
        d = max(0, min(d, N - 1));
        atomicAdd(&h[d >> 7], 1);  // NPC=128
    }
    __syncthreads();
    int* hg = hist1 + (size_t)b * C;
    for (int i = t; i < C; i += 256) hg[i] = h[i];
}

// fused: column sums -> exclusive scan -> convert hist1 to per-(block,bucket) cursors
__global__ __launch_bounds__(1024) void k_p1scan(int* __restrict__ hist1, int C,
                                                 int* __restrict__ cbase) {
    __shared__ int col[CLDS];
    __shared__ int sdata[1024];
    int t = threadIdx.x;
    for (int i = t; i < C; i += 1024) {
        int sum = 0;
        for (int b = 0; b < P1; b++) sum += hist1[(size_t)b * C + i];
        col[i] = sum;
    }
    __syncthreads();
    int v = (t < C) ? col[t] : 0;
    sdata[t] = v;
    __syncthreads();
    for (int off = 1; off < 1024; off <<= 1) {
        int x = (t >= off) ? sdata[t - off] : 0;
        __syncthreads();
        sdata[t] += x;
        __syncthreads();
    }
    int pos = sdata[t] - v;  // exclusive
    if (t < C) cbase[t] = pos;
    if (t == 1023) cbase[C] = sdata[1023];
    if (t < C) {
        int run = pos;
        for (int b = 0; b < P1; b++) {
            size_t idx = (size_t)b * C + t;
            int c = hist1[idx];
            hist1[idx] = run;
            run += c;
        }
    }
}

// scatter packed (dst_local_coarse<<17 | src) into coarse regions, LDS cursors only
__global__ __launch_bounds__(256) void k_p1fill(const int* __restrict__ src,
                                                const int* __restrict__ dst, int E, int N, int C,
                                                int chunk, const int* __restrict__ hist1,
                                                uint* __restrict__ binned1) {
    __shared__ int cur[CLDS];
    int t = threadIdx.x, b = blockIdx.x;
    const int* hg = hist1 + (size_t)b * C;
    for (int i = t; i < C; i += 256) cur[i] = hg[i];
    __syncthreads();
    int e0 = b * chunk, e1 = min(e0 + chunk, E);
    for (int e = e0 + t; e < e1; e += 256) {
        int d = dst[e];
        d = max(0, min(d, N - 1));
        int s = src[e];
        s = max(0, min(s, N - 1));
        int p = atomicAdd(&cur[d >> 7], 1);
        binned1[p] = ((uint)(d & (NPC - 1)) << 17) | (uint)s;
    }
}

// pass 2: one block per coarse bucket -> per-node CSR (rowptr/deg/dinv) + sorted ssrc
__global__ __launch_bounds__(256) void k_p2(const uint* __restrict__ binned1,
                                            const int* __restrict__ cbase, int N,
                                            int* __restrict__ ssrc, int* __restrict__ rowptr,
                                            int* __restrict__ deg, float* __restrict__ dinv) {
    __shared__ int ncnt[NPC], nbase_[NPC];
    int c = blockIdx.x, t = threadIdx.x;
    int start = cbase[c], end = cbase[c + 1];
    if (t < NPC) ncnt[t] = 0;
    __syncthreads();
    for (int j = start + t; j < end; j += 256) atomicAdd(&ncnt[binned1[j] >> 17], 1);
    __syncthreads();
    if (t == 0) {
        int run = start;
        for (int i = 0; i < NPC; i++) {
            nbase_[i] = run;
            run += ncnt[i];
        }
    }
    __syncthreads();
    if (t < NPC) {
        int node = c * NPC + t;
        if (node < N) {
            deg[node] = ncnt[t];
            rowptr[node] = nbase_[t];
            dinv[node] = rsqrtf((float)ncnt[t] + 1.0f);
        }
    }
    __syncthreads();
    if (t < NPC) ncnt[t] = nbase_[t];  // reuse as cursors
    __syncthreads();
    for (int j = start + t; j < end; j += 256) {
        uint pe = binned1[j];
        int p = atomicAdd(&ncnt[pe >> 17], 1);
        ssrc[p] = (int)(pe & 0x1FFFFu);
    }
}

// ---- GEMM1: hs_b = bf16( dinv[i] * (x @ W1) ) ------------------------------

__global__ __launch_bounds__(256) void k_gemm1(const float* __restrict__ x,
                                               const float* __restrict__ W1,
                                               const float* __restrict__ dinv, int N,
                                               uint* __restrict__ hs_b) {
    __shared__ float Wl[8 * 516];
    __shared__ float xl[32 * 132];
    int t = threadIdx.x;
    int fg = t & 7, rs = t >> 3;
    int row0 = blockIdx.x * 128;
    float acc[4][16];
#pragma unroll
    for (int a = 0; a < 4; a++)
#pragma unroll
        for (int b = 0; b < 16; b++) acc[a][b] = 0.f;

    for (int cb = 0; cb < 4; cb++) {
        __syncthreads();
        for (int i = t; i < 4096; i += 256) {
            int kk = i >> 7, f = i & 127;
            Wl[(f >> 4) * 516 + kk * 16 + (f & 15)] = W1[(size_t)(cb * 32 + kk) * 128 + f];
        }
        for (int i = t; i < 4096; i += 256) {
            int r = i >> 5, kk = i & 31;
            int gr = row0 + r;
            xl[kk * 132 + r] = (gr < N) ? x[(size_t)gr * 128 + cb * 32 + kk] : 0.f;
        }
        __syncthreads();
        const float* wb = &Wl[fg * 516];
        const float* xb = &xl[rs * 4];
#pragma unroll 4
        for (int kk = 0; kk < 32; kk++) {
            float4 xv = *(const float4*)&xb[kk * 132];
            float4 w0 = *(const float4*)&wb[kk * 16];
            float4 w1 = *(const float4*)&wb[kk * 16 + 4];
            float4 w2 = *(const float4*)&wb[kk * 16 + 8];
            float4 w3 = *(const float4*)&wb[kk * 16 + 12];
            float xr[4] = {xv.x, xv.y, xv.z, xv.w};
            float wf[16] = {w0.x, w0.y, w0.z, w0.w, w1.x, w1.y, w1.z, w1.w,
                            w2.x, w2.y, w2.z, w2.w, w3.x, w3.y, w3.z, w3.w};
#pragma unroll
            for (int a = 0; a < 4; a++)
#pragma unroll
                for (int b = 0; b < 16; b++) acc[a][b] = fmaf(xr[a], wf[b], acc[a][b]);
        }
    }
#pragma unroll
    for (int a = 0; a < 4; a++) {
        int gr = row0 + rs * 4 + a;
        if (gr < N) {
            float sc = dinv[gr];
            uint o[8];
#pragma unroll
            for (int q = 0; q < 8; q++) o[q] = pk(acc[a][2 * q] * sc, acc[a][2 * q + 1] * sc);
            *(uint4*)&hs_b[(size_t)gr * 64 + fg * 8] = make_uint4(o[0], o[1], o[2], o[3]);
            *(uint4*)&hs_b[(size_t)gr * 64 + fg * 8 + 4] = make_uint4(o[4], o[5], o[6], o[7]);
        }
    }
}

// ---- AGG1: wave per node, gather-sum bf16 rows, no atomics -----------------

__global__ __launch_bounds__(256) void k_agg1(const uint* __restrict__ hs_b,
                                              const int* __restrict__ rowptr,
                                              const int* __restrict__ deg,
                                              const int* __restrict__ ssrc,
                                              const float* __restrict__ dinv,
                                              const float2* __restrict__ b1, int N,
                                              uint* __restrict__ rh_b) {
    int w = threadIdx.x >> 6, lane = threadIdx.x & 63;
    int d = blockIdx.x * 4 + w;
    if (d >= N) return;
    int start = rowptr[d], cnt = deg[d];
    uint sv = hs_b[(size_t)d * 64 + lane];  // self-loop
    float a0 = bflo(sv), a1 = bfhi(sv);
    int j = 0;
    for (; j + 4 <= cnt; j += 4) {
        int i0 = ssrc[start + j], i1 = ssrc[start + j + 1];
        int i2 = ssrc[start + j + 2], i3 = ssrc[start + j + 3];
        uint u0 = hs_b[(size_t)i0 * 64 + lane];
        uint u1 = hs_b[(size_t)i1 * 64 + lane];
        uint u2 = hs_b[(size_t)i2 * 64 + lane];
        uint u3 = hs_b[(size_t)i3 * 64 + lane];
        a0 += bflo(u0) + bflo(u1) + bflo(u2) + bflo(u3);
        a1 += bfhi(u0) + bfhi(u1) + bfhi(u2) + bfhi(u3);
    }
    for (; j < cnt; j++) {
        uint u = hs_b[(size_t)ssrc[start + j] * 64 + lane];
        a0 += bflo(u);
        a1 += bfhi(u);
    }
    float sc = dinv[d];
    float2 bb = b1[lane];
    rh_b[(size_t)d * 64 + lane] =
        pk(fmaxf(fmaf(a0, sc, bb.x), 0.f), fmaxf(fmaf(a1, sc, bb.y), 0.f));
}

// ---- GEMM2: h2_b = bf16( dinv[i] * (rh @ W2) ), one row per thread ---------

__global__ __launch_bounds__(256) void k_gemm2(const uint* __restrict__ rh_b,
                                               const float* __restrict__ W2,
                                               const float* __restrict__ dinv, int N,
                                               uint* __restrict__ h2_b) {
    __shared__ float Wl[D_H * D_OUT];  // 8 KB
    int t = threadIdx.x;
    for (int i = t; i < D_H * D_OUT; i += 256) Wl[i] = W2[i];
    __syncthreads();
    int r = blockIdx.x * 256 + t;
    if (r >= N) return;
    const uint* xrow = rh_b + (size_t)r * 64;
    float acc[16];
#pragma unroll
    for (int f = 0; f < 16; f++) acc[f] = 0.f;
    for (int c = 0; c < 16; c++) {
        uint4 xv = *(const uint4*)(xrow + c * 4);
        uint xs[4] = {xv.x, xv.y, xv.z, xv.w};
#pragma unroll
        for (int u = 0; u < 4; u++) {
            int k = c * 8 + u * 2;
            float x0 = bflo(xs[u]), x1 = bfhi(xs[u]);
            const float* w0 = &Wl[k * 16];
            const float* w1 = &Wl[(k + 1) * 16];
#pragma unroll
            for (int f = 0; f < 16; f++) acc[f] = fmaf(x0, w0[f], acc[f]);
#pragma unroll
            for (int f = 0; f < 16; f++) acc[f] = fmaf(x1, w1[f], acc[f]);
        }
    }
    float sc = dinv[r];
    uint o[8];
#pragma unroll
    for (int q = 0; q < 8; q++) o[q] = pk(acc[2 * q] * sc, acc[2 * q + 1] * sc);
    *(uint4*)&h2_b[(size_t)r * 8] = make_uint4(o[0], o[1], o[2], o[3]);
    *(uint4*)&h2_b[(size_t)r * 8 + 4] = make_uint4(o[4], o[5], o[6], o[7]);
}

// ---- AGG2: wave per node (8 edge slots x 8 uint-features), shfl reduce -----

__global__ __launch_bounds__(256) void k_agg2(const uint* __restrict__ h2_b,
                                              const int* __restrict__ rowptr,
                                              const int* __restrict__ deg,
                                              const int* __restrict__ ssrc,
                                              const float* __restrict__ dinv,
                                              const float* __restrict__ b2, int N,
                                              float2* __restrict__ out) {
    int w = threadIdx.x >> 6, lane = threadIdx.x & 63;
    int d = blockIdx.x * 4 + w;
    if (d >= N) return;
    int slot = lane >> 3, jp = lane & 7;
    int start = rowptr[d], cnt = deg[d];
    float a0 = 0.f, a1 = 0.f;
    if (slot == 0) {
        uint sv = h2_b[(size_t)d * 8 + jp];  // self-loop
        a0 = bflo(sv);
        a1 = bfhi(sv);
    }
    for (int j = slot; j < cnt; j += 8) {
        uint hv = h2_b[(size_t)ssrc[start + j] * 8 + jp];
        a0 += bflo(hv);
        a1 += bfhi(hv);
    }
    a0 += __shfl_xor(a0, 8);
    a1 += __shfl_xor(a1, 8);
    a0 += __shfl_xor(a0, 16);
    a1 += __shfl_xor(a1, 16);
    a0 += __shfl_xor(a0, 32);
    a1 += __shfl_xor(a1, 32);
    if (slot == 0) {
        float di = dinv[d];
        out[(size_t)d * 8 + jp] =
            make_float2(fmaf(a0, di, b2[2 * jp]), fmaf(a1, di, b2[2 * jp + 1]));
    }
}

// ---- launch ----------------------------------------------------------------

extern "C" void kernel_launch(void* const* d_in, const int* in_sizes, int n_in,
                              void* d_out, int out_size, void* d_ws, size_t ws_size,
                              hipStream_t stream) {
    const float* x  = (const float*)d_in[0];
    const int*   ei = (const int*)d_in[1];
    const float* W1 = (const float*)d_in[2];
    const float* b1 = (const float*)d_in[3];
    const float* W2 = (const float*)d_in[4];
    const float* b2 = (const float*)d_in[5];
    int N = in_sizes[0] / D_IN;
    int E = in_sizes[1] / 2;
    const int* src = ei;
    const int* dst = ei + E;
    int C = (N + NPC - 1) / NPC;           // 782
    int chunk = (E + P1 - 1) / P1;         // 6250

    char* ws = (char*)d_ws;
    size_t off = 0;
    auto alloc = [&](size_t bytes) -> char* {
        char* p = ws + off;
        off = (off + bytes + 255) & ~(size_t)255;
        return p;
    };
    int*   hist1   = (int*)alloc((size_t)P1 * C * 4);       // 800 KB
    int*   cbase   = (int*)alloc((size_t)(C + 1) * 4);
    uint*  binned1 = (uint*)alloc((size_t)E * 4);
    int*   ssrc    = (int*)alloc((size_t)E * 4);
    int*   rowptr  = (int*)alloc((size_t)N * 4);
    int*   deg     = (int*)alloc((size_t)N * 4);
    float* dinv    = (float*)alloc((size_t)N * 4);
    uint*  hs_b    = (uint*)alloc((size_t)N * 64 * 4);      // 25.6 MB bf16-packed
    uint*  rh_b    = (uint*)alloc((size_t)N * 64 * 4);
    uint*  h2_b    = hs_b;  // hs_b dead after k_agg1; reuse

    k_p1hist<<<P1, 256, 0, stream>>>(dst, E, N, C, chunk, hist1);
    k_p1scan<<<1, 1024, 0, stream>>>(hist1, C, cbase);
    k_p1fill<<<P1, 256, 0, stream>>>(src, dst, E, N, C, chunk, hist1, binned1);
    k_p2<<<C, 256, 0, stream>>>(binned1, cbase, N, ssrc, rowptr, deg, dinv);
    k_gemm1<<<(N + 127) / 128, 256, 0, stream>>>(x, W1, dinv, N, hs_b);
    k_agg1<<<(N + 3) / 4, 256, 0, stream>>>(hs_b, rowptr, deg, ssrc, dinv,
                                            (const float2*)b1, N, rh_b);
    k_gemm2<<<(N + 255) / 256, 256, 0, stream>>>(rh_b, W2, dinv, N, h2_b);
    k_agg2<<<(N + 3) / 4, 256, 0, stream>>>(h2_b, rowptr, deg, ssrc, dinv, b2, N,
                                            (float2*)d_out);
}

// Round 6
// 329.274 us; speedup vs baseline: 4.3592x; 1.1153x over previous
//
#include <hip/hip_runtime.h>

typedef unsigned int uint;
typedef __attribute__((ext_vector_type(8))) short bf16x8;
typedef __attribute__((ext_vector_type(4))) float f32x4;

#define D_IN 128
#define D_H  128
#define D_OUT 16
#define NPC 512                // nodes per coarse bucket
#define NPCSH 9
#define CLDS 224               // >= C = ceil(N/NPC) = 196
#define P1 256                 // pass-1 blocks
#define XL_STRIDE 68
#define WT_STRIDE 68

static __device__ __forceinline__ float bflo(uint u) { return __uint_as_float(u << 16); }
static __device__ __forceinline__ float bfhi(uint u) { return __uint_as_float(u & 0xFFFF0000u); }
static __device__ __forceinline__ uint f2bf(float f) {
    uint b = __float_as_uint(f);
    return (b + 0x7FFFu + ((b >> 16) & 1u)) >> 16;  // RNE
}
static __device__ __forceinline__ uint pk(float a, float b) {
    return f2bf(a) | (f2bf(b) << 16);
}

// ---- pass 1: coarse histogram (private LDS, no global atomics) -------------

__global__ __launch_bounds__(256) void k_p1hist(const int* __restrict__ dst, int E, int N, int C,
                                                int chunk, int* __restrict__ hist1) {
    __shared__ int h[CLDS];
    int t = threadIdx.x, b = blockIdx.x;
    for (int i = t; i < C; i += 256) h[i] = 0;
    __syncthreads();
    int e0 = b * chunk, e1 = min(e0 + chunk, E);
    for (int e = e0 + t; e < e1; e += 256) {
        int d = dst[e];
        d = max(0, min(d, N - 1));
        atomicAdd(&h[d >> NPCSH], 1);
    }
    __syncthreads();
    int* hg = hist1 + (size_t)b * C;
    for (int i = t; i < C; i += 256) hg[i] = h[i];
}

// fused: column sums -> exclusive scan -> convert hist1 to per-(block,bucket) cursors
__global__ __launch_bounds__(1024) void k_p1scan(int* __restrict__ hist1, int C,
                                                 int* __restrict__ cbase) {
    __shared__ int col[CLDS];
    __shared__ int sdata[1024];
    int t = threadIdx.x;
    for (int i = t; i < C; i += 1024) {
        int sum = 0;
        for (int b = 0; b < P1; b++) sum += hist1[(size_t)b * C + i];
        col[i] = sum;
    }
    __syncthreads();
    int v = (t < C) ? col[t] : 0;
    sdata[t] = v;
    __syncthreads();
    for (int off = 1; off < 1024; off <<= 1) {
        int x = (t >= off) ? sdata[t - off] : 0;
        __syncthreads();
        sdata[t] += x;
        __syncthreads();
    }
    int pos = sdata[t] - v;  // exclusive
    if (t < C) cbase[t] = pos;
    if (t == 1023) cbase[C] = sdata[1023];
    if (t < C) {
        int run = pos;
        for (int b = 0; b < P1; b++) {
            size_t idx = (size_t)b * C + t;
            int c = hist1[idx];
            hist1[idx] = run;
            run += c;
        }
    }
}

// scatter packed (dst_local_coarse<<17 | src) into coarse regions, LDS cursors only
__global__ __launch_bounds__(256) void k_p1fill(const int* __restrict__ src,
                                                const int* __restrict__ dst, int E, int N, int C,
                                                int chunk, const int* __restrict__ hist1,
                                                uint* __restrict__ binned1) {
    __shared__ int cur[CLDS];
    int t = threadIdx.x, b = blockIdx.x;
    const int* hg = hist1 + (size_t)b * C;
    for (int i = t; i < C; i += 256) cur[i] = hg[i];
    __syncthreads();
    int e0 = b * chunk, e1 = min(e0 + chunk, E);
    for (int e = e0 + t; e < e1; e += 256) {
        int d = dst[e];
        d = max(0, min(d, N - 1));
        int s = src[e];
        s = max(0, min(s, N - 1));
        int p = atomicAdd(&cur[d >> NPCSH], 1);
        binned1[p] = ((uint)(d & (NPC - 1)) << 17) | (uint)s;
    }
}

// pass 2: one block per coarse bucket -> per-node CSR (rowptr/deg/dinv) + sorted ssrc
__global__ __launch_bounds__(256) void k_p2(const uint* __restrict__ binned1,
                                            const int* __restrict__ cbase, int N,
                                            int* __restrict__ ssrc, int* __restrict__ rowptr,
                                            int* __restrict__ deg, float* __restrict__ dinv) {
    __shared__ int ncnt[NPC], nbase_[NPC];
    __shared__ int sdata[256];
    int c = blockIdx.x, t = threadIdx.x;
    int start = cbase[c], end = cbase[c + 1];
    for (int i = t; i < NPC; i += 256) ncnt[i] = 0;
    __syncthreads();
    for (int j = start + t; j < end; j += 256) atomicAdd(&ncnt[binned1[j] >> 17], 1);
    __syncthreads();
    // parallel exclusive scan, 2 elements per thread (order-preserving)
    int v0 = ncnt[2 * t], v1 = ncnt[2 * t + 1];
    int s = v0 + v1;
    sdata[t] = s;
    __syncthreads();
    for (int off = 1; off < 256; off <<= 1) {
        int xv = (t >= off) ? sdata[t - off] : 0;
        __syncthreads();
        sdata[t] += xv;
        __syncthreads();
    }
    int pre = sdata[t] - s;
    nbase_[2 * t] = start + pre;
    nbase_[2 * t + 1] = start + pre + v0;
    __syncthreads();
    for (int i = t; i < NPC; i += 256) {
        int node = c * NPC + i;
        if (node < N) {
            deg[node] = ncnt[i];
            rowptr[node] = nbase_[i];
            dinv[node] = rsqrtf((float)ncnt[i] + 1.0f);
        }
    }
    __syncthreads();
    for (int i = t; i < NPC; i += 256) ncnt[i] = nbase_[i];  // reuse as cursors
    __syncthreads();
    for (int j = start + t; j < end; j += 256) {
        uint pe = binned1[j];
        int p = atomicAdd(&ncnt[pe >> 17], 1);
        ssrc[p] = (int)(pe & 0x1FFFFu);
    }
}

// ---- GEMM1 (MFMA): hs_b = bf16( dinv[i] * (x @ W1) ) -----------------------
// block: 64 rows x 128 cols. wave w: col-tiles {2w,2w+1}, all 4 row-tiles.
// A frag: A[m=lane&15][k=(lane>>4)*8+j]; B frag: B[k=(lane>>4)*8+j][n=lane&15];
// D: row=(lane>>4)*4+r, col=lane&15.

__global__ __launch_bounds__(256) void k_gemm1(const float* __restrict__ x,
                                               const float* __restrict__ W1,
                                               const float* __restrict__ dinv, int N,
                                               uint* __restrict__ hs_b) {
    __shared__ uint Wt[128 * WT_STRIDE];  // [f][k2] bf16 pairs, 34.8 KB
    __shared__ uint xl[64 * XL_STRIDE];   // [row][k2] bf16 pairs, 17.4 KB; reused as out
    int t = threadIdx.x;
    int row0 = blockIdx.x * 64;
    // stage W1 transposed as bf16 pairs
    for (int p = t; p < 64 * 128; p += 256) {
        int k2 = p >> 7, f = p & 127;
        float w0 = W1[(size_t)(2 * k2) * 128 + f];
        float w1 = W1[(size_t)(2 * k2 + 1) * 128 + f];
        Wt[f * WT_STRIDE + k2] = pk(w0, w1);
    }
    // stage x rows as bf16 pairs
    const float2* x2 = (const float2*)x;
    for (int p = t; p < 64 * 64; p += 256) {
        int r = p >> 6, c = p & 63;
        int gr = row0 + r;
        float2 v = (gr < N) ? x2[(size_t)gr * 64 + c] : make_float2(0.f, 0.f);
        xl[r * XL_STRIDE + c] = pk(v.x, v.y);
    }
    __syncthreads();
    int w = t >> 6, lane = t & 63;
    int q = lane >> 4, m = lane & 15;
    // preload all A fragments (xl dead afterwards)
    bf16x8 afr[4][4];
#pragma unroll
    for (int rt = 0; rt < 4; rt++)
#pragma unroll
        for (int kc = 0; kc < 4; kc++)
            afr[rt][kc] = *(const bf16x8*)&xl[(rt * 16 + m) * XL_STRIDE + kc * 16 + q * 4];
    f32x4 acc[2][4];
#pragma unroll
    for (int c = 0; c < 2; c++)
#pragma unroll
        for (int rt = 0; rt < 4; rt++) acc[c][rt] = (f32x4){0.f, 0.f, 0.f, 0.f};
#pragma unroll
    for (int c = 0; c < 2; c++) {
        int f = w * 32 + c * 16 + m;
#pragma unroll
        for (int kc = 0; kc < 4; kc++) {
            bf16x8 bfr = *(const bf16x8*)&Wt[f * WT_STRIDE + kc * 16 + q * 4];
#pragma unroll
            for (int rt = 0; rt < 4; rt++)
                acc[c][rt] =
                    __builtin_amdgcn_mfma_f32_16x16x32_bf16(afr[rt][kc], bfr, acc[c][rt], 0, 0, 0);
        }
    }
    __syncthreads();  // all waves done reading xl
    uint* outl = xl;  // 64 x 65 packed out tile
#pragma unroll
    for (int rt = 0; rt < 4; rt++) {
        int gb = row0 + rt * 16 + q * 4;
        float4 dv;
        if (gb + 3 < N) {
            dv = *(const float4*)&dinv[gb];
        } else {
            dv.x = (gb < N) ? dinv[gb] : 0.f;
            dv.y = (gb + 1 < N) ? dinv[gb + 1] : 0.f;
            dv.z = (gb + 2 < N) ? dinv[gb + 2] : 0.f;
            dv.w = (gb + 3 < N) ? dinv[gb + 3] : 0.f;
        }
        float dr[4] = {dv.x, dv.y, dv.z, dv.w};
#pragma unroll
        for (int c = 0; c < 2; c++) {
            f32x4 a = acc[c][rt];
#pragma unroll
            for (int r = 0; r < 4; r++) {
                float v = a[r] * dr[r];
                float vn = __shfl_xor(v, 1);
                if (!(lane & 1)) {
                    int row = rt * 16 + q * 4 + r;
                    int cp = (w * 32 + c * 16 + m) >> 1;
                    outl[row * 65 + cp] = pk(v, vn);
                }
            }
        }
    }
    __syncthreads();
    for (int p = t; p < 64 * 64; p += 256) {
        int r = p >> 6, cc = p & 63;
        int gr = row0 + r;
        if (gr < N) hs_b[(size_t)gr * 64 + cc] = outl[r * 65 + cc];
    }
}

// ---- AGG1: wave per node, gather-sum bf16 rows, no atomics -----------------

__global__ __launch_bounds__(256) void k_agg1(const uint* __restrict__ hs_b,
                                              const int* __restrict__ rowptr,
                                              const int* __restrict__ deg,
                                              const int* __restrict__ ssrc,
                                              const float* __restrict__ dinv,
                                              const float2* __restrict__ b1, int N,
                                              uint* __restrict__ rh_b) {
    int w = threadIdx.x >> 6, lane = threadIdx.x & 63;
    int d = blockIdx.x * 4 + w;
    if (d >= N) return;
    int start = rowptr[d], cnt = deg[d];
    uint sv = hs_b[(size_t)d * 64 + lane];  // self-loop
    float a0 = bflo(sv), a1 = bfhi(sv);
    int j = 0;
    for (; j + 4 <= cnt; j += 4) {
        int i0 = ssrc[start + j], i1 = ssrc[start + j + 1];
        int i2 = ssrc[start + j + 2], i3 = ssrc[start + j + 3];
        uint u0 = hs_b[(size_t)i0 * 64 + lane];
        uint u1 = hs_b[(size_t)i1 * 64 + lane];
        uint u2 = hs_b[(size_t)i2 * 64 + lane];
        uint u3 = hs_b[(size_t)i3 * 64 + lane];
        a0 += bflo(u0) + bflo(u1) + bflo(u2) + bflo(u3);
        a1 += bfhi(u0) + bfhi(u1) + bfhi(u2) + bfhi(u3);
    }
    for (; j < cnt; j++) {
        uint u = hs_b[(size_t)ssrc[start + j] * 64 + lane];
        a0 += bflo(u);
        a1 += bfhi(u);
    }
    float sc = dinv[d];
    float2 bb = b1[lane];
    rh_b[(size_t)d * 64 + lane] =
        pk(fmaxf(fmaf(a0, sc, bb.x), 0.f), fmaxf(fmaf(a1, sc, bb.y), 0.f));
}

// ---- GEMM2: h2_b = bf16( dinv[i] * (rh @ W2) ), one row per thread ---------

__global__ __launch_bounds__(256) void k_gemm2(const uint* __restrict__ rh_b,
                                               const float* __restrict__ W2,
                                               const float* __restrict__ dinv, int N,
                                               uint* __restrict__ h2_b) {
    __shared__ float Wl[D_H * D_OUT];  // 8 KB
    int t = threadIdx.x;
    for (int i = t; i < D_H * D_OUT; i += 256) Wl[i] = W2[i];
    __syncthreads();
    int r = blockIdx.x * 256 + t;
    if (r >= N) return;
    const uint* xrow = rh_b + (size_t)r * 64;
    float acc[16];
#pragma unroll
    for (int f = 0; f < 16; f++) acc[f] = 0.f;
    for (int c = 0; c < 16; c++) {
        uint4 xv = *(const uint4*)(xrow + c * 4);
        uint xs[4] = {xv.x, xv.y, xv.z, xv.w};
#pragma unroll
        for (int u = 0; u < 4; u++) {
            int k = c * 8 + u * 2;
            float x0 = bflo(xs[u]), x1 = bfhi(xs[u]);
            const float* w0 = &Wl[k * 16];
            const float* w1 = &Wl[(k + 1) * 16];
#pragma unroll
            for (int f = 0; f < 16; f++) acc[f] = fmaf(x0, w0[f], acc[f]);
#pragma unroll
            for (int f = 0; f < 16; f++) acc[f] = fmaf(x1, w1[f], acc[f]);
        }
    }
    float sc = dinv[r];
    uint o[8];
#pragma unroll
    for (int q = 0; q < 8; q++) o[q] = pk(acc[2 * q] * sc, acc[2 * q + 1] * sc);
    *(uint4*)&h2_b[(size_t)r * 8] = make_uint4(o[0], o[1], o[2], o[3]);
    *(uint4*)&h2_b[(size_t)r * 8 + 4] = make_uint4(o[4], o[5], o[6], o[7]);
}

// ---- AGG2: wave per node (8 edge slots x 8 uint-features), shfl reduce -----

__global__ __launch_bounds__(256) void k_agg2(const uint* __restrict__ h2_b,
                                              const int* __restrict__ rowptr,
                                              const int* __restrict__ deg,
                                              const int* __restrict__ ssrc,
                                              const float* __restrict__ dinv,
                                              const float* __restrict__ b2, int N,
                                              float2* __restrict__ out) {
    int w = threadIdx.x >> 6, lane = threadIdx.x & 63;
    int d = blockIdx.x * 4 + w;
    if (d >= N) return;
    int slot = lane >> 3, jp = lane & 7;
    int start = rowptr[d], cnt = deg[d];
    float a0 = 0.f, a1 = 0.f;
    if (slot == 0) {
        uint sv = h2_b[(size_t)d * 8 + jp];  // self-loop
        a0 = bflo(sv);
        a1 = bfhi(sv);
    }
    for (int j = slot; j < cnt; j += 8) {
        uint hv = h2_b[(size_t)ssrc[start + j] * 8 + jp];
        a0 += bflo(hv);
        a1 += bfhi(hv);
    }
    a0 += __shfl_xor(a0, 8);
    a1 += __shfl_xor(a1, 8);
    a0 += __shfl_xor(a0, 16);
    a1 += __shfl_xor(a1, 16);
    a0 += __shfl_xor(a0, 32);
    a1 += __shfl_xor(a1, 32);
    if (slot == 0) {
        float di = dinv[d];
        out[(size_t)d * 8 + jp] =
            make_float2(fmaf(a0, di, b2[2 * jp]), fmaf(a1, di, b2[2 * jp + 1]));
    }
}

// ---- launch ----------------------------------------------------------------

extern "C" void kernel_launch(void* const* d_in, const int* in_sizes, int n_in,
                              void* d_out, int out_size, void* d_ws, size_t ws_size,
                              hipStream_t stream) {
    const float* x  = (const float*)d_in[0];
    const int*   ei = (const int*)d_in[1];
    const float* W1 = (const float*)d_in[2];
    const float* b1 = (const float*)d_in[3];
    const float* W2 = (const float*)d_in[4];
    const float* b2 = (const float*)d_in[5];
    int N = in_sizes[0] / D_IN;
    int E = in_sizes[1] / 2;
    const int* src = ei;
    const int* dst = ei + E;
    int C = (N + NPC - 1) / NPC;           // 196
    int chunk = (E + P1 - 1) / P1;         // 6250

    char* ws = (char*)d_ws;
    size_t off = 0;
    auto alloc = [&](size_t bytes) -> char* {
        char* p = ws + off;
        off = (off + bytes + 255) & ~(size_t)255;
        return p;
    };
    int*   hist1   = (int*)alloc((size_t)P1 * C * 4);
    int*   cbase   = (int*)alloc((size_t)(C + 1) * 4);
    uint*  binned1 = (uint*)alloc((size_t)E * 4);
    int*   ssrc    = (int*)alloc((size_t)E * 4);
    int*   rowptr  = (int*)alloc((size_t)N * 4);
    int*   deg     = (int*)alloc((size_t)N * 4);
    float* dinv    = (float*)alloc((size_t)N * 4);
    uint*  hs_b    = (uint*)alloc((size_t)N * 64 * 4);      // 25.6 MB bf16-packed
    uint*  rh_b    = (uint*)alloc((size_t)N * 64 * 4);
    uint*  h2_b    = hs_b;  // hs_b dead after k_agg1; reuse

    k_p1hist<<<P1, 256, 0, stream>>>(dst, E, N, C, chunk, hist1);
    k_p1scan<<<1, 1024, 0, stream>>>(hist1, C, cbase);
    k_p1fill<<<P1, 256, 0, stream>>>(src, dst, E, N, C, chunk, hist1, binned1);
    k_p2<<<C, 256, 0, stream>>>(binned1, cbase, N, ssrc, rowptr, deg, dinv);
    k_gemm1<<<(N + 63) / 64, 256, 0, stream>>>(x, W1, dinv, N, hs_b);
    k_agg1<<<(N + 3) / 4, 256, 0, stream>>>(hs_b, rowptr, deg, ssrc, dinv,
                                            (const float2*)b1, N, rh_b);
    k_gemm2<<<(N + 255) / 256, 256, 0, stream>>>(rh_b, W2, dinv, N, h2_b);
    k_agg2<<<(N + 3) / 4, 256, 0, stream>>>(h2_b, rowptr, deg, ssrc, dinv, b2, N,
                                            (float2*)d_out);
}